// Round 1
// baseline (169.344 us; speedup 1.0000x reference)
//
#include <hip/hip_runtime.h>
#include <hip/hip_bf16.h>
#include <stdint.h>

#define N1 8192
#define N2 16384
#define DIM 256
#define NSPLIT 16
#define BM 128
#define BN 128
#define BK 64
#define COLS_PER_SPLIT (N2 / NSPLIT)        // 1024
#define NT_PER_SPLIT (COLS_PER_SPLIT / BN)  // 8
#define NPART (NSPLIT * 2)                  // 32 partial top3 sets per row

typedef short v8s  __attribute__((ext_vector_type(8)));   // 8 x bf16 bits
typedef float f32x4 __attribute__((ext_vector_type(4)));

#define GLD16(g, l)                                                                         \
  __builtin_amdgcn_global_load_lds((const __attribute__((address_space(1))) uint32_t*)(g),  \
                                   (__attribute__((address_space(3))) uint32_t*)(l), 16, 0, 0)

__device__ __forceinline__ void top3_insert(float v, float& t0, float& t1, float& t2) {
    // invariant t0 >= t1 >= t2; 3 VALU ops
    float nt1 = __builtin_amdgcn_fmed3f(v, t0, t1);
    float nt2 = __builtin_amdgcn_fmed3f(v, t1, t2);
    t0 = fmaxf(t0, v);
    t1 = nt1;
    t2 = nt2;
}

// One wave per row over A then B: fp32 sumsq, rsqrt, emit bf16 normalized row.
__global__ __launch_bounds__(256) void normalize_kernel(
        const float* __restrict__ inA, const float* __restrict__ inB,
        __hip_bfloat16* __restrict__ outA, __hip_bfloat16* __restrict__ outB) {
    const int gw   = blockIdx.x * 4 + (threadIdx.x >> 6);
    const int lane = threadIdx.x & 63;
    const float* in;
    __hip_bfloat16* out;
    int row;
    if (gw < N1) { in = inA; out = outA; row = gw; }
    else         { in = inB; out = outB; row = gw - N1; }
    const float4 v = *(const float4*)(in + (size_t)row * DIM + lane * 4);
    float s = v.x * v.x + v.y * v.y + v.z * v.z + v.w * v.w;
    #pragma unroll
    for (int off = 32; off; off >>= 1) s += __shfl_xor(s, off, 64);
    const float inv = 1.0f / sqrtf(s);
    __hip_bfloat16 o[4];
    o[0] = __float2bfloat16(v.x * inv);
    o[1] = __float2bfloat16(v.y * inv);
    o[2] = __float2bfloat16(v.z * inv);
    o[3] = __float2bfloat16(v.w * inv);
    *(uint2*)(out + (size_t)row * DIM + lane * 4) = *(uint2*)o;
}

// 8 global_load_lds (A: 128x64 16KB half + B: 128x64 16KB half) per round/wave.
__device__ __forceinline__ void stage8(const char* ag, const char* bg,
                                       char* al, char* bl) {
    #pragma unroll
    for (int j = 0; j < 4; ++j) {
        GLD16(ag + (size_t)j * 4096, al + j * 1024);
        GLD16(bg + (size_t)j * 4096, bl + j * 1024);
    }
}

// Block: 4 waves over a 128x128 C-tile; wave = 64x64 (4rt x 4ct of 16x16).
// BK=64 + double-buffered LDS (2 x (16KB A + 16KB B) = 64KB -> still 2 blocks/CU).
// Counted-vmcnt pipeline (T3/T4): issue next round's 8 global_load_lds, then
// s_waitcnt vmcnt(8) + raw s_barrier — the in-flight loads cross the barrier and
// land during this round's 32 MFMAs. This replaces the old __syncthreads() whose
// implicit vmcnt(0) drain exposed full staging latency every round (MfmaUtil 33%).
// XOR swizzle slot8 = chunk ^ (row&7) folded into the global-side lane permutation
// -> <=2-way (free) ds_read_b128 conflicts, zero ds_writes.
__global__ __launch_bounds__(256, 2) void gemm_top3_kernel(
        const __hip_bfloat16* __restrict__ A, const __hip_bfloat16* __restrict__ B,
        float* __restrict__ partial) {
    __shared__ char smem[2 * 32768];        // [buf][A 16KB | B 16KB]

    const int tid  = threadIdx.x;
    const int wave = tid >> 6;
    const int lane = tid & 63;
    const int lo   = lane & 15;
    const int quad = lane >> 4;
    const int rb    = blockIdx.x >> 4;     // 64 row-blocks
    const int split = blockIdx.x & 15;     // consecutive blocks -> different XCDs
    const int row0 = rb * BM;
    const int C0   = split * COLS_PER_SPLIT;
    const int wr = (wave >> 1) * 64;       // wave row-half
    const int wc = (wave & 1) * 64;        // wave col-half

    // --- staging lane constants: lane i handles row (i>>3), fetches the chunk
    // that lands (via linear global_load_lds dest) in physical slot (i&7):
    // chunk c = (i&7) ^ row&7  (store-side of the XOR swizzle).
    const int srow   = lane >> 3;                    // 0..7
    const int schunk = (lane & 7) ^ srow;            // swizzled fetch chunk
    const size_t gl_off = (size_t)srow * 512 + (size_t)schunk * 16;

    const char* Ag = (const char*)A + ((size_t)(row0 + wave * 32)) * 512 + gl_off;
    const char* Bg = (const char*)B + ((size_t)(C0   + wave * 32)) * 512 + gl_off;
    char* AldsW = smem + wave * 4096;          // + buf*32768 + j*1024
    char* BldsW = smem + 16384 + wave * 4096;

    // --- ds_read offsets (read-side swizzle: slot = (ks*4+quad) ^ (row&7)) ---
    int aoff[2], boff[2];
    #pragma unroll
    for (int ks = 0; ks < 2; ++ks) {
        const int swz = ((ks * 4 + quad) ^ (lo & 7)) * 16;
        aoff[ks] = (wr + lo) * 128 + swz;
        boff[ks] = 16384 + (wc + lo) * 128 + swz;
    }

    float t0[16], t1[16], t2[16];
    #pragma unroll
    for (int i = 0; i < 16; i++) { t0[i] = -1e30f; t1[i] = -1e30f; t2[i] = -1e30f; }

    // prologue: stage round 0 into buf0
    stage8(Ag, Bg, AldsW, BldsW);

    for (int nt = 0; nt < NT_PER_SPLIT; ++nt) {
        f32x4 acc[4][4];
        #pragma unroll
        for (int kk = 0; kk < 4; ++kk) {
            const int cur = kk & 1;        // nt*4 is even -> buffer parity == kk&1
            // issue next round's loads into buf[cur^1] (read last round; freed by
            // the closing barrier below), then wait only for the PREVIOUS 8.
            if ((kk < 3) || (nt < NT_PER_SPLIT - 1)) {
                const int nt2 = (kk == 3) ? nt + 1 : nt;
                const int kk2 = (kk + 1) & 3;
                stage8(Ag + kk2 * 128,
                       Bg + (size_t)nt2 * 65536 + kk2 * 128,
                       AldsW + (cur ^ 1) * 32768, BldsW + (cur ^ 1) * 32768);
                asm volatile("s_waitcnt vmcnt(8)" ::: "memory");
            } else {
                asm volatile("s_waitcnt vmcnt(0)" ::: "memory");
            }
            __builtin_amdgcn_s_barrier();          // all waves' buf[cur] loads landed
            __builtin_amdgcn_sched_barrier(0);

            const char* base = smem + cur * 32768;
            #pragma unroll
            for (int ks = 0; ks < 2; ++ks) {
                v8s af[4];
                #pragma unroll
                for (int rt = 0; rt < 4; rt++)
                    af[rt] = *(const v8s*)(base + aoff[ks] + rt * 2048);
                #pragma unroll
                for (int ct = 0; ct < 4; ct++) {
                    v8s bf = *(const v8s*)(base + boff[ks] + ct * 2048);
                    #pragma unroll
                    for (int rt = 0; rt < 4; rt++) {
                        if (kk == 0 && ks == 0)
                            acc[rt][ct] = __builtin_amdgcn_mfma_f32_16x16x32_bf16(
                                af[rt], bf, (f32x4){0.f, 0.f, 0.f, 0.f}, 0, 0, 0);
                        else
                            acc[rt][ct] = __builtin_amdgcn_mfma_f32_16x16x32_bf16(
                                af[rt], bf, acc[rt][ct], 0, 0, 0);
                    }
                }
            }
            asm volatile("s_waitcnt lgkmcnt(0)" ::: "memory");  // reads of buf[cur] done
            __builtin_amdgcn_sched_barrier(0);
            __builtin_amdgcn_s_barrier();          // buf[cur] free for restaging
        }
        // fold this N-tile's 64 C-values/lane into the running top3
        #pragma unroll
        for (int rt = 0; rt < 4; rt++)
            #pragma unroll
            for (int r = 0; r < 4; r++) {
                const int i = rt * 4 + r;
                #pragma unroll
                for (int ct = 0; ct < 4; ct++)
                    top3_insert(acc[rt][ct][r], t0[i], t1[i], t2[i]);
            }
    }

    // merge across the 16 lanes sharing rows (different col residues)
    #pragma unroll
    for (int step = 1; step < 16; step <<= 1) {
        #pragma unroll
        for (int i = 0; i < 16; i++) {
            float b0 = __shfl_xor(t0[i], step, 64);
            float b1 = __shfl_xor(t1[i], step, 64);
            float b2 = __shfl_xor(t2[i], step, 64);
            top3_insert(b0, t0[i], t1[i], t2[i]);
            top3_insert(b1, t0[i], t1[i], t2[i]);
            top3_insert(b2, t0[i], t1[i], t2[i]);
        }
    }

    if (lo == 0) {
        #pragma unroll
        for (int rt = 0; rt < 4; rt++)
            #pragma unroll
            for (int r = 0; r < 4; r++) {
                const int i = rt * 4 + r;
                const int row = row0 + wr + rt * 16 + quad * 4 + r;
                float* p = partial + ((size_t)row * NPART + (split * 2 + (wave & 1))) * 3;
                p[0] = t0[i]; p[1] = t1[i]; p[2] = t2[i];
            }
    }
}

__global__ __launch_bounds__(256) void merge_kernel(
        const float* __restrict__ partial, float* __restrict__ out) {
    const int row = blockIdx.x * 256 + threadIdx.x;
    if (row >= N1) return;
    const float* p = partial + (size_t)row * NPART * 3;
    float t0 = -1e30f, t1 = -1e30f, t2 = -1e30f;
    #pragma unroll
    for (int i = 0; i < NPART * 3; i++) top3_insert(p[i], t0, t1, t2);
    out[row] = (t0 + t1 + t2) * (1.0f / 3.0f);
}

extern "C" void kernel_launch(void* const* d_in, const int* in_sizes, int n_in,
                              void* d_out, int out_size, void* d_ws, size_t ws_size,
                              hipStream_t stream) {
    const float* tA = (const float*)d_in[0];
    const float* tB = (const float*)d_in[1];
    float* out = (float*)d_out;

    __hip_bfloat16* An = (__hip_bfloat16*)d_ws;
    __hip_bfloat16* Bn = An + (size_t)N1 * DIM;
    float* partial = (float*)(Bn + (size_t)N2 * DIM);

    normalize_kernel<<<(N1 + N2) / 4, 256, 0, stream>>>(tA, tB, An, Bn);
    gemm_top3_kernel<<<(N1 / BM) * NSPLIT, 256, 0, stream>>>(An, Bn, partial);
    merge_kernel<<<N1 / 256, 256, 0, stream>>>(partial, out);
}

// Round 2
// 150.272 us; speedup vs baseline: 1.1269x; 1.1269x over previous
//
#include <hip/hip_runtime.h>
#include <hip/hip_bf16.h>
#include <stdint.h>

#define N1 8192
#define N2 16384
#define DIM 256
#define BM 128            // rows per block
#define NTILES 16         // 256-col tiles per block (block spans 4096 cols)
#define CBLK 4            // col-blocks: 16384 / 4096
#define NPART CBLK        // partial top3 sets per row

typedef short v8s  __attribute__((ext_vector_type(8)));   // 8 x bf16 bits
typedef float f32x4 __attribute__((ext_vector_type(4)));

#define GLD16(g, l)                                                                         \
  __builtin_amdgcn_global_load_lds((const __attribute__((address_space(1))) uint32_t*)(g),  \
                                   (__attribute__((address_space(3))) uint32_t*)(l), 16, 0, 0)

__device__ __forceinline__ void top3_insert(float v, float& t0, float& t1, float& t2) {
    float nt1 = __builtin_amdgcn_fmed3f(v, t0, t1);
    float nt2 = __builtin_amdgcn_fmed3f(v, t1, t2);
    t0 = fmaxf(t0, v);
    t1 = nt1;
    t2 = nt2;
}

// One wave per row over A then B: fp32 sumsq, rsqrt, emit bf16 normalized row.
__global__ __launch_bounds__(256) void normalize_kernel(
        const float* __restrict__ inA, const float* __restrict__ inB,
        __hip_bfloat16* __restrict__ outA, __hip_bfloat16* __restrict__ outB) {
    const int gw   = blockIdx.x * 4 + (threadIdx.x >> 6);
    const int lane = threadIdx.x & 63;
    const float* in;
    __hip_bfloat16* out;
    int row;
    if (gw < N1) { in = inA; out = outA; row = gw; }
    else         { in = inB; out = outB; row = gw - N1; }
    const float4 v = *(const float4*)(in + (size_t)row * DIM + lane * 4);
    float s = v.x * v.x + v.y * v.y + v.z * v.z + v.w * v.w;
    #pragma unroll
    for (int off = 32; off; off >>= 1) s += __shfl_xor(s, off, 64);
    const float inv = 1.0f / sqrtf(s);
    __hip_bfloat16 o[4];
    o[0] = __float2bfloat16(v.x * inv);
    o[1] = __float2bfloat16(v.y * inv);
    o[2] = __float2bfloat16(v.z * inv);
    o[3] = __float2bfloat16(v.w * inv);
    *(uint2*)(out + (size_t)row * DIM + lane * 4) = *(uint2*)o;
}

// Stage one 16KB half (128 rows x 64 K bf16) via 2 global_load_lds per thread.
// Chunk g = (j*8+wave)*64+lane lands at lds_slot + g*16 (HW: uniform base + lane*16).
// XOR swizzle slot8 is folded into the global source: sc = (lane&7) ^ ((lane>>3)&7).
__device__ __forceinline__ void stage_half(const char* src_rows, int kk, char* lds_slot,
                                           int wave, int rbase, int sc16) {
    GLD16(src_rows + (size_t)rbase * 512 + kk * 128 + sc16, lds_slot + wave * 1024);
    GLD16(src_rows + (size_t)(rbase + 64) * 512 + kk * 128 + sc16,
          lds_slot + (8 + wave) * 1024);
}

// 8-phase-class schedule (T3+T4+T5) for M=8192,N=16384,K=256.
// Block: 512 thr = 8 waves (2m x 4n); wave tile 64x64; block 128 rows x 256 cols/nt,
// nt=0..15 (4096 cols). K-tile stream Ts = nt*4+k (BK=64), 2 phases per K-tile
// (h=0: rows 0-31 of wave + load bf; h=1: rows 32-63), 16 MFMA per phase.
// LDS ring 112KB: A x3 slots (Ts%3), B x2x2 halves (Ts&1). Stage 2 tiles ahead:
//   even phase of Ts: stage A(Ts+2);  odd phase of Ts: stage both B(Ts+2) halves.
// Slot-lifetime audit (phase stage vs last reader, barrier-separated):
//   A(Ts+2)->slot (Ts+2)%3: last read odd phase of Ts-1  (>=2 phases earlier)  OK
//   B(Ts+2)->par Ts&1:      last read even phase of Ts   (1 phase earlier)     OK
// Gates: vmcnt(6) at end of each odd phase (allows the 6 loads staged this
// tile-pair to stay in flight; guarantees tile Ts+1 landed). Never 0 until the
// stream drains (vmcnt(0) once at nt=15,P=5). Loads get ~2.5 phases of cover.
__global__ __launch_bounds__(512, 2) void gemm_top3_kernel(
        const __hip_bfloat16* __restrict__ A, const __hip_bfloat16* __restrict__ B,
        float* __restrict__ partial) {
    __shared__ char smem[114688];   // A: 3x16KB @0, B: 2par x 2half x16KB @49152

    const int tid  = threadIdx.x;
    const int wave = tid >> 6;
    const int lane = tid & 63;
    const int lo   = lane & 15;
    const int quad = lane >> 4;
    const int m    = wave >> 2;      // 0..1 row-half
    const int n    = wave & 3;       // 0..3 col-quarter
    const int rb   = blockIdx.x >> 2;
    const int cb   = blockIdx.x & 3; // consecutive bids -> different XCDs share cb%4
    const int row0 = rb * BM;

    // staging lane constants
    const int rbase = wave * 8 + (lane >> 3);
    const int sc16  = ((lane & 7) ^ ((lane >> 3) & 7)) << 4;
    const char* Ab = (const char*)A + (size_t)row0 * 512;
    const char* Bb = (const char*)B + (size_t)cb * 4096 * 512;

    // read-side swizzle: physical chunk = (ks*4+quad) ^ (row&7)
    const int swz[2] = { (quad ^ (lo & 7)) << 4, ((4 + quad) ^ (lo & 7)) << 4 };

    f32x4 acc[4][4];
    #pragma unroll
    for (int i = 0; i < 4; ++i)
        #pragma unroll
        for (int j = 0; j < 4; ++j) acc[i][j] = (f32x4){0.f, 0.f, 0.f, 0.f};
    float t0[16], t1[16], t2[16];
    #pragma unroll
    for (int i = 0; i < 16; ++i) { t0[i] = -1e30f; t1[i] = -1e30f; t2[i] = -1e30f; }

    // --- prologue: stage T0 fully, then T1; allow T1 (6 loads) in flight ---
    stage_half(Ab, 0, smem, wave, rbase, sc16);                              // A(T0)
    stage_half(Bb, 0, smem + 49152, wave, rbase, sc16);                      // B(T0)h0
    stage_half(Bb + 128 * 512, 0, smem + 49152 + 16384, wave, rbase, sc16);  // B(T0)h1
    stage_half(Ab, 1, smem + 16384, wave, rbase, sc16);                      // A(T1)
    stage_half(Bb, 1, smem + 49152 + 32768, wave, rbase, sc16);              // B(T1)h0
    stage_half(Bb + 128 * 512, 1, smem + 49152 + 49152, wave, rbase, sc16);  // B(T1)h1
    asm volatile("s_waitcnt vmcnt(6)" ::: "memory");
    __builtin_amdgcn_s_barrier();

    int am = 0;                      // (nt*4) % 3
    v8s bf[4][2];                    // current K-tile B frags (loaded at h==0)
    for (int nt = 0; nt < NTILES; ++nt) {
        #pragma unroll
        for (int P = 0; P < 8; ++P) {
            const int k = P >> 1, h = P & 1, par = k & 1;
            int sA = am + k; if (sA >= 3) sA -= 3;
            // --- ds reads for this phase ---
            v8s af[2][2];
            const char* ap = smem + sA * 16384 + (m * 64 + h * 32 + lo) * 128;
            #pragma unroll
            for (int rt = 0; rt < 2; ++rt)
                #pragma unroll
                for (int ks = 0; ks < 2; ++ks)
                    af[rt][ks] = *(const v8s*)(ap + rt * 2048 + swz[ks]);
            if (h == 0) {
                const char* bp = smem + 49152 + par * 32768 + (n >> 1) * 16384
                               + ((n & 1) * 64 + lo) * 128;
                #pragma unroll
                for (int ct = 0; ct < 4; ++ct)
                    #pragma unroll
                    for (int ks = 0; ks < 2; ++ks)
                        bf[ct][ks] = *(const v8s*)(bp + ct * 2048 + swz[ks]);
            }
            // --- stage 2 tiles ahead ---
            if (h == 0) {
                if (!(nt == NTILES - 1 && k >= 2)) {
                    int s2 = am + k + 2;
                    if (s2 >= 3) s2 -= 3;
                    if (s2 >= 3) s2 -= 3;
                    stage_half(Ab, (k + 2) & 3, smem + s2 * 16384, wave, rbase, sc16);
                }
            } else {
                if (!(nt == NTILES - 1 && k >= 2)) {
                    const int kb  = (k + 2) & 3;
                    const char* bsrc = Bb + (size_t)((nt + (k >> 1)) * 256) * 512;
                    char* bdst = smem + 49152 + par * 32768;
                    stage_half(bsrc, kb, bdst, wave, rbase, sc16);
                    stage_half(bsrc + 128 * 512, kb, bdst + 16384, wave, rbase, sc16);
                }
            }
            __builtin_amdgcn_s_barrier();
            __builtin_amdgcn_s_setprio(1);
            #pragma unroll
            for (int ks = 0; ks < 2; ++ks)
                #pragma unroll
                for (int ct = 0; ct < 4; ++ct)
                    #pragma unroll
                    for (int rt = 0; rt < 2; ++rt)
                        acc[h * 2 + rt][ct] = __builtin_amdgcn_mfma_f32_16x16x32_bf16(
                            af[rt][ks], bf[ct][ks], acc[h * 2 + rt][ct], 0, 0, 0);
            __builtin_amdgcn_s_setprio(0);
            if (h == 1) {
                if (nt == NTILES - 1 && P == 5) {
                    asm volatile("s_waitcnt vmcnt(0)" ::: "memory");   // stream drained
                } else if (!(nt == NTILES - 1 && P == 7)) {
                    asm volatile("s_waitcnt vmcnt(6)" ::: "memory");   // counted gate
                }
            }
            __builtin_amdgcn_s_barrier();
        }
        // --- fold this 256-col tile into running top3, reset acc ---
        #pragma unroll
        for (int i = 0; i < 4; ++i)
            #pragma unroll
            for (int r = 0; r < 4; ++r) {
                const int s = i * 4 + r;
                #pragma unroll
                for (int ct = 0; ct < 4; ++ct) {
                    top3_insert(acc[i][ct][r], t0[s], t1[s], t2[s]);
                    acc[i][ct][r] = 0.f;
                }
            }
        am = (am == 2) ? 0 : am + 1;
    }

    // merge across the 16 lanes sharing rows (different col residues)
    #pragma unroll
    for (int step = 1; step < 16; step <<= 1) {
        #pragma unroll
        for (int s = 0; s < 16; ++s) {
            float b0 = __shfl_xor(t0[s], step, 64);
            float b1 = __shfl_xor(t1[s], step, 64);
            float b2 = __shfl_xor(t2[s], step, 64);
            top3_insert(b0, t0[s], t1[s], t2[s]);
            top3_insert(b1, t0[s], t1[s], t2[s]);
            top3_insert(b2, t0[s], t1[s], t2[s]);
        }
    }

    // cross-wave (4 n-waves per row) merge via LDS, then one partial per row
    float* fbuf = (float*)smem;      // [128 rows][4 n][3]
    if (lo == 0) {
        #pragma unroll
        for (int s = 0; s < 16; ++s) {
            const int row = m * 64 + (s >> 2) * 16 + quad * 4 + (s & 3);
            float* p = fbuf + row * 12 + n * 3;
            p[0] = t0[s]; p[1] = t1[s]; p[2] = t2[s];
        }
    }
    __syncthreads();
    if (tid < BM) {
        const float* p = fbuf + tid * 12;
        float u0 = p[0], u1 = p[1], u2 = p[2];
        #pragma unroll
        for (int i = 3; i < 12; ++i) top3_insert(p[i], u0, u1, u2);
        float* o = partial + ((size_t)(row0 + tid) * NPART + cb) * 3;
        o[0] = u0; o[1] = u1; o[2] = u2;
    }
}

__global__ __launch_bounds__(256) void merge_kernel(
        const float* __restrict__ partial, float* __restrict__ out) {
    const int row = blockIdx.x * 256 + threadIdx.x;
    if (row >= N1) return;
    const float* p = partial + (size_t)row * NPART * 3;
    float t0 = -1e30f, t1 = -1e30f, t2 = -1e30f;
    #pragma unroll
    for (int i = 0; i < NPART * 3; i++) top3_insert(p[i], t0, t1, t2);
    out[row] = (t0 + t1 + t2) * (1.0f / 3.0f);
}

extern "C" void kernel_launch(void* const* d_in, const int* in_sizes, int n_in,
                              void* d_out, int out_size, void* d_ws, size_t ws_size,
                              hipStream_t stream) {
    const float* tA = (const float*)d_in[0];
    const float* tB = (const float*)d_in[1];
    float* out = (float*)d_out;

    __hip_bfloat16* An = (__hip_bfloat16*)d_ws;
    __hip_bfloat16* Bn = An + (size_t)N1 * DIM;
    float* partial = (float*)(Bn + (size_t)N2 * DIM);

    normalize_kernel<<<(N1 + N2) / 4, 256, 0, stream>>>(tA, tB, An, Bn);
    gemm_top3_kernel<<<(N1 / BM) * CBLK, 512, 0, stream>>>(An, Bn, partial);
    merge_kernel<<<N1 / 256, 256, 0, stream>>>(partial, out);
}